// Round 5
// baseline (1562.382 us; speedup 1.0000x reference)
//
#include <hip/hip_runtime.h>
#include <math.h>

#define GRPO_BETA 0.1f

constexpr int BM = 128;    // rows per block tile
constexpr int BN = 256;    // vocab cols per block tile (chunk width)
constexpr int BK = 32;     // k-slab; LDS rows hold 2 slabs (128B, double-buffered)

typedef __attribute__((ext_vector_type(4))) float   f32x4;
typedef __attribute__((ext_vector_type(8))) __bf16  bf16x8;
typedef __attribute__((ext_vector_type(4))) __bf16  bf16x4;

// NaN-safe exp for lse merges: args expected <= 0; fminf(NaN,0)=0.
__device__ __forceinline__ float sexp_fast(float a) { return __expf(fminf(a, 0.f)); }
__device__ __forceinline__ float sexp(float a)      { return expf(fminf(a, 0.f)); }

__device__ __forceinline__ bf16x4 cvt4(float4 v) {
  bf16x4 r;
  r[0] = (__bf16)v.x; r[1] = (__bf16)v.y; r[2] = (__bf16)v.z; r[3] = (__bf16)v.w;
  return r;
}

// barrier WITHOUT vmcnt drain: LDS writes made visible (lgkmcnt), global
// prefetch loads stay in flight across the barrier (T4-minimum).
__device__ __forceinline__ void bar_lgkm() {
  asm volatile("s_waitcnt lgkmcnt(0)\n\ts_barrier" ::: "memory");
}

// ---------------------------------------------------------------------------
// Kernel 1: bf16-MFMA GEMM (logits = A[M,K] x W[V,K]^T), f32 inputs converted
// in-kernel, fused per-row per-256-col-chunk reductions.
// LDS layout: [row][128B] where byte x of row r lives at r*128 + (x ^ ((r&7)<<4)).
//   bytes [0,64) = even k-slab, [64,128) = odd (modulo the swizzle's bit-6 mix,
//   which read & write sides apply identically).
// Pipeline (unroll-2, two prefetch reg sets, ONE lgkm-barrier per slab):
//   step s: issue loads slab s+2 -> setE | MFMA(half s&1) | stage setO(slab
//   s+1) -> other half | bar.  Loads are in flight ~1.8 steps.
// grid = (gx*NC) XCD-remapped, block = 512 (8 waves: 2M x 4N, wave tile 64x64)
// ---------------------------------------------------------------------------
template <bool POLICY>
__global__ __launch_bounds__(512)
void mfma_gemm_reduce(const float* __restrict__ A,
                      const float* __restrict__ W,
                      float* __restrict__ part,
                      int M, int K, int V, int NC, int NL, int gx)
{
  __shared__ __align__(16) unsigned short lds_a[BM * 64];   // 16 KB (2 slabs)
  __shared__ __align__(16) unsigned short lds_w[BN * 64];   // 32 KB (2 slabs)
  __shared__ __align__(16) float4 lds_red[BM * 4];          // 8 KB

  const int tid  = threadIdx.x;
  const int lane = tid & 63;
  const int wave = tid >> 6;      // 0..7
  const int wm   = wave >> 2;     // 0..1  (M half)
  const int wn   = wave & 3;      // 0..3  (N quarter)
  const int l15  = lane & 15;
  const int q    = lane >> 4;     // 0..3

  // ---- XCD-aware block remap (bijective when nb % 8 == 0) ----
  const int nb  = gridDim.x;
  int wl = blockIdx.x;
  if ((nb & 7) == 0) wl = (wl & 7) * (nb >> 3) + (wl >> 3);
  const int bx    = wl % gx;
  const int chunk = wl / gx;
  const int row0  = bx * BM;

  // ---- staging map: t7 covers 4 floats at k = t7*4 within a slab ----
  const int t7 = tid & 7;
  const int tr = tid >> 3;        // 0..63 row group
  const int st0 = tr * 128 + ((t7 * 8) ^ ((tr & 7) << 4));

  int aro[2];
#pragma unroll
  for (int i = 0; i < 2; ++i) aro[i] = min(row0 + tr + 64 * i, M - 1) * K;

  // ---- fragment read byte offsets (slab parity = bit 6; frag f adds 2048) ----
  const int swzr  = ((q * 16) ^ ((l15 & 7) << 4));
  const int aoff0 = (wm * 64 + l15) * 128 + swzr;
  const int woff0 = (wn * 64 + l15) * 128 + swzr;

  // running per-row records (threads 0..127 own local row = tid)
  float rm = -INFINITY, rse = 0.f, rsum = 0.f;
  int   ridx = 0x7fffffff;

  const int NS = K / BK;

  for (int sub = 0; sub < NL; ++sub) {
    const int v0 = (chunk * NL + sub) * BN;
    if (v0 >= V) break;

    int wro[4];
#pragma unroll
    for (int i = 0; i < 4; ++i) wro[i] = min(v0 + tr + 64 * i, V - 1) * K;

    f32x4 acc[4][4];
#pragma unroll
    for (int i = 0; i < 4; ++i)
#pragma unroll
      for (int j = 0; j < 4; ++j) acc[i][j] = (f32x4){0.f, 0.f, 0.f, 0.f};

    // ---- prologue: sets E (even slabs) and O (odd slabs) ----
    float4 arE[2], wrE[4], arO[2], wrO[4];
#pragma unroll
    for (int i = 0; i < 2; ++i) arE[i] = *reinterpret_cast<const float4*>(A + aro[i] + t7 * 4);
#pragma unroll
    for (int i = 0; i < 4; ++i) wrE[i] = *reinterpret_cast<const float4*>(W + wro[i] + t7 * 4);
    if (NS > 1) {
#pragma unroll
      for (int i = 0; i < 2; ++i) arO[i] = *reinterpret_cast<const float4*>(A + aro[i] + BK + t7 * 4);
#pragma unroll
      for (int i = 0; i < 4; ++i) wrO[i] = *reinterpret_cast<const float4*>(W + wro[i] + BK + t7 * 4);
    }
#pragma unroll
    for (int i = 0; i < 2; ++i)
      *reinterpret_cast<bf16x4*>(reinterpret_cast<char*>(lds_a) + st0 + i * 8192) = cvt4(arE[i]);
#pragma unroll
    for (int i = 0; i < 4; ++i)
      *reinterpret_cast<bf16x4*>(reinterpret_cast<char*>(lds_w) + st0 + i * 8192) = cvt4(wrE[i]);
    bar_lgkm();

    // ---- main K-loop: unroll-2, 1 barrier per slab ----
    for (int s = 0; s < NS; s += 2) {
      // ===== even step: compute slab s (half 0) =====
      if (s + 2 < NS) {             // issue slab s+2 -> set E (long in-flight)
        const int kf = (s + 2) * BK + t7 * 4;
#pragma unroll
        for (int i = 0; i < 2; ++i) arE[i] = *reinterpret_cast<const float4*>(A + aro[i] + kf);
#pragma unroll
        for (int i = 0; i < 4; ++i) wrE[i] = *reinterpret_cast<const float4*>(W + wro[i] + kf);
      }
      {
        bf16x8 afr[4];
#pragma unroll
        for (int f = 0; f < 4; ++f)
          afr[f] = *reinterpret_cast<const bf16x8*>(
              reinterpret_cast<const char*>(lds_a) + aoff0 + f * 2048);
        __builtin_amdgcn_s_setprio(1);
#pragma unroll
        for (int fn = 0; fn < 4; ++fn) {
          bf16x8 wfr = *reinterpret_cast<const bf16x8*>(
              reinterpret_cast<const char*>(lds_w) + woff0 + fn * 2048);
#pragma unroll
          for (int fm = 0; fm < 4; ++fm)
            acc[fm][fn] = __builtin_amdgcn_mfma_f32_16x16x32_bf16(
                afr[fm], wfr, acc[fm][fn], 0, 0, 0);
        }
        __builtin_amdgcn_s_setprio(0);
      }
      if (s + 1 < NS) {             // stage slab s+1 (set O) -> half 1
#pragma unroll
        for (int i = 0; i < 2; ++i)
          *reinterpret_cast<bf16x4*>(reinterpret_cast<char*>(lds_a) + (st0 ^ 64) + i * 8192) = cvt4(arO[i]);
#pragma unroll
        for (int i = 0; i < 4; ++i)
          *reinterpret_cast<bf16x4*>(reinterpret_cast<char*>(lds_w) + (st0 ^ 64) + i * 8192) = cvt4(wrO[i]);
      }
      bar_lgkm();

      // ===== odd step: compute slab s+1 (half 1) =====
      if (s + 1 < NS) {
        if (s + 3 < NS) {           // issue slab s+3 -> set O
          const int kf = (s + 3) * BK + t7 * 4;
#pragma unroll
          for (int i = 0; i < 2; ++i) arO[i] = *reinterpret_cast<const float4*>(A + aro[i] + kf);
#pragma unroll
          for (int i = 0; i < 4; ++i) wrO[i] = *reinterpret_cast<const float4*>(W + wro[i] + kf);
        }
        {
          bf16x8 afr[4];
#pragma unroll
          for (int f = 0; f < 4; ++f)
            afr[f] = *reinterpret_cast<const bf16x8*>(
                reinterpret_cast<const char*>(lds_a) + (aoff0 ^ 64) + f * 2048);
          __builtin_amdgcn_s_setprio(1);
#pragma unroll
          for (int fn = 0; fn < 4; ++fn) {
            bf16x8 wfr = *reinterpret_cast<const bf16x8*>(
                reinterpret_cast<const char*>(lds_w) + (woff0 ^ 64) + fn * 2048);
#pragma unroll
            for (int fm = 0; fm < 4; ++fm)
              acc[fm][fn] = __builtin_amdgcn_mfma_f32_16x16x32_bf16(
                  afr[fm], wfr, acc[fm][fn], 0, 0, 0);
          }
          __builtin_amdgcn_s_setprio(0);
        }
        if (s + 2 < NS) {           // stage slab s+2 (set E) -> half 0
#pragma unroll
          for (int i = 0; i < 2; ++i)
            *reinterpret_cast<bf16x4*>(reinterpret_cast<char*>(lds_a) + st0 + i * 8192) = cvt4(arE[i]);
#pragma unroll
          for (int i = 0; i < 4; ++i)
            *reinterpret_cast<bf16x4*>(reinterpret_cast<char*>(lds_w) + st0 + i * 8192) = cvt4(wrE[i]);
        }
        bar_lgkm();
      }
    }

    // ---- fused epilogue: per-row reduction over this 256-col sub-tile ----
    // C/D layout: col = lane&15, row = (lane>>4)*4 + reg  [verified m89/m91]
    // Max-first: find row max (4 shfl), THEN exp against final max (no online
    // rescale in the shuffle chain); argmax by exact equality + integer min.
#pragma unroll
    for (int fm = 0; fm < 4; ++fm) {
#pragma unroll
      for (int reg = 0; reg < 4; ++reg) {
        float lm = -INFINITY;
#pragma unroll
        for (int fn = 0; fn < 4; ++fn) {
          const int v = v0 + wn * 64 + fn * 16 + l15;
          if (v < V) lm = fmaxf(lm, acc[fm][fn][reg]);
        }
#pragma unroll
        for (int d = 1; d < 16; d <<= 1) lm = fmaxf(lm, __shfl_xor(lm, d));
        // lm == exact row max (within this 64-col wave tile)
        float se = 0.f, sm = 0.f; int li = 0x7fffffff;
#pragma unroll
        for (int fn = 0; fn < 4; ++fn) {
          const int v = v0 + wn * 64 + fn * 16 + l15;
          if (v < V) {
            const float x = acc[fm][fn][reg];
            se += __expf(x - lm);
            sm += x;
            if (x == lm) li = min(li, v);
          }
        }
#pragma unroll
        for (int d = 1; d < 16; d <<= 1) {
          se += __shfl_xor(se, d);
          sm += __shfl_xor(sm, d);
          li  = min(li, __shfl_xor(li, d));
        }
        if (l15 == 0) {
          const int row = wm * 64 + fm * 16 + q * 4 + reg;
          lds_red[row * 4 + wn] = make_float4(lm, se, sm, __int_as_float(li));
        }
      }
    }
    __syncthreads();

    if (tid < BM) {
      float4 p = lds_red[tid * 4];
      float m = p.x, se = p.y, sm = p.z; int idx = __float_as_int(p.w);
#pragma unroll
      for (int j = 1; j < 4; ++j) {
        const float4 t = lds_red[tid * 4 + j];
        const int ti = __float_as_int(t.w);
        const float nm = fmaxf(m, t.x);
        se = se * sexp_fast(m - nm) + t.y * sexp_fast(t.x - nm);
        sm += t.z;
        if (t.x > m || (t.x == m && ti < idx)) idx = ti;
        m = nm;
      }
      const float nm = fmaxf(rm, m);
      rse = rse * sexp_fast(rm - nm) + se * sexp_fast(m - nm);
      rsum += sm;
      if (m > rm || (m == rm && idx < ridx)) ridx = idx;
      rm = nm;
    }
    __syncthreads();  // lds_red / lds tiles free for next sub
  }

  if (tid < BM) {
    const int row = row0 + tid;
    if (row < M) {
      if (POLICY) {
        reinterpret_cast<float4*>(part)[(size_t)row * NC + chunk] =
            make_float4(rm, rse, rsum, __int_as_float(ridx));
      } else {
        reinterpret_cast<float2*>(part)[(size_t)row * NC + chunk] =
            make_float2(rm, rse);
      }
    }
  }
}

// ---------------------------------------------------------------------------
// Kernel 2: per-row combine of chunk partials + gathered ref dot (f32 exact).
// Writes rowtab[row] = {tok_lp, kl, mean_v(log_probs_row), 0}
// grid = (M), block = 256
// ---------------------------------------------------------------------------
__global__ __launch_bounds__(256)
void combine_kernel(const float4* __restrict__ partP,
                    const float2* __restrict__ partR,
                    const float* __restrict__ refA,
                    const float* __restrict__ refW,
                    float4* __restrict__ rowtab,
                    int M, int K, int V, int NC)
{
  const int row = blockIdx.x;
  const int tid = threadIdx.x;

  __shared__ float redf[256];
  __shared__ int   redi[256];
  __shared__ float s_M, s_SE, s_SUM, s_Mr, s_SEr, s_dot;
  __shared__ int   s_idx;

  float m = -INFINITY, se = 0.f, sm = 0.f; int idx = 0x7fffffff;
  for (int i = tid; i < NC; i += 256) {
    float4 p = partP[(size_t)row * NC + i];
    int pi = __float_as_int(p.w);
    float nm = fmaxf(m, p.x);
    se = se * sexp(m - nm) + p.y * sexp(p.x - nm);
    if (p.x > m || (p.x == m && pi < idx)) idx = pi;
    m = nm;
    sm += p.z;
  }
  redf[tid] = m; redi[tid] = idx;
  __syncthreads();
  for (int s = 128; s > 0; s >>= 1) {
    if (tid < s) {
      float om = redf[tid + s]; int oi = redi[tid + s];
      if (om > redf[tid] || (om == redf[tid] && oi < redi[tid])) { redf[tid] = om; redi[tid] = oi; }
    }
    __syncthreads();
  }
  if (tid == 0) { s_M = redf[0]; s_idx = redi[0]; }
  __syncthreads();
  const float Mp = s_M; const int chosen = s_idx;

  float contrib = se * sexp(m - Mp);
  __syncthreads();
  redf[tid] = contrib; __syncthreads();
  for (int s = 128; s > 0; s >>= 1) { if (tid < s) redf[tid] += redf[tid + s]; __syncthreads(); }
  if (tid == 0) s_SE = redf[0];
  __syncthreads();
  redf[tid] = sm; __syncthreads();
  for (int s = 128; s > 0; s >>= 1) { if (tid < s) redf[tid] += redf[tid + s]; __syncthreads(); }
  if (tid == 0) s_SUM = redf[0];
  __syncthreads();

  float mr = -INFINITY, ser = 0.f;
  for (int i = tid; i < NC; i += 256) {
    float2 p = partR[(size_t)row * NC + i];
    float nm = fmaxf(mr, p.x);
    ser = ser * sexp(mr - nm) + p.y * sexp(p.x - nm);
    mr = nm;
  }
  redf[tid] = mr; __syncthreads();
  for (int s = 128; s > 0; s >>= 1) { if (tid < s) redf[tid] = fmaxf(redf[tid], redf[tid + s]); __syncthreads(); }
  if (tid == 0) s_Mr = redf[0];
  __syncthreads();
  const float Mr = s_Mr;
  float contribr = ser * sexp(mr - Mr);
  __syncthreads();
  redf[tid] = contribr; __syncthreads();
  for (int s = 128; s > 0; s >>= 1) { if (tid < s) redf[tid] += redf[tid + s]; __syncthreads(); }
  if (tid == 0) s_SEr = redf[0];
  __syncthreads();

  float dp = 0.f;
  const float* ar = refA + (size_t)row * K;
  const float* wr = refW + (size_t)chosen * K;
  for (int j = tid * 4; j < K; j += 256 * 4) {
    float4 x = *reinterpret_cast<const float4*>(ar + j);
    float4 y = *reinterpret_cast<const float4*>(wr + j);
    dp = fmaf(x.x, y.x, dp);
    dp = fmaf(x.y, y.y, dp);
    dp = fmaf(x.z, y.z, dp);
    dp = fmaf(x.w, y.w, dp);
  }
  __syncthreads();
  redf[tid] = dp; __syncthreads();
  for (int s = 128; s > 0; s >>= 1) { if (tid < s) redf[tid] += redf[tid + s]; __syncthreads(); }
  if (tid == 0) s_dot = redf[0];
  __syncthreads();

  if (tid == 0) {
    float lse     = Mp + logf(s_SE);
    float tok     = Mp - lse;
    float ref_lse = Mr + logf(s_SEr);
    float ref_tok = s_dot - ref_lse;
    float d  = ref_tok - tok;
    float kl = expm1f(d) - d;
    float rm3 = s_SUM / (float)V - lse;
    rowtab[row] = make_float4(tok, kl, rm3, 0.f);
  }
}

// ---------------------------------------------------------------------------
// Kernel 3: final reduction over rows -> 5 scalar outputs. grid=(1), block=256
// ---------------------------------------------------------------------------
__global__ __launch_bounds__(256)
void final_kernel(const float4* __restrict__ rowtab,
                  const float* __restrict__ mask,
                  const float* __restrict__ rewards,
                  float* __restrict__ out,
                  int M, int B, int T)
{
  const int tid = threadIdx.x;
  __shared__ float redf[256];
  __shared__ float s_mean, s_m3, s_var;
  __shared__ float s_kl[16], s_cnt[16];

  float st = 0.f, sm3 = 0.f;
  for (int r = tid; r < M; r += 256) {
    float4 v = rowtab[r];
    st += v.x; sm3 += v.z;
  }
  redf[tid] = st; __syncthreads();
  for (int s = 128; s > 0; s >>= 1) { if (tid < s) redf[tid] += redf[tid + s]; __syncthreads(); }
  if (tid == 0) s_mean = redf[0] / (float)M;
  __syncthreads();
  redf[tid] = sm3; __syncthreads();
  for (int s = 128; s > 0; s >>= 1) { if (tid < s) redf[tid] += redf[tid + s]; __syncthreads(); }
  if (tid == 0) s_m3 = redf[0] / (float)M;
  __syncthreads();

  const float mean = s_mean;
  float sv = 0.f;
  for (int r = tid; r < M; r += 256) { float d = rowtab[r].x - mean; sv = fmaf(d, d, sv); }
  __syncthreads();
  redf[tid] = sv; __syncthreads();
  for (int s = 128; s > 0; s >>= 1) { if (tid < s) redf[tid] += redf[tid + s]; __syncthreads(); }
  if (tid == 0) s_var = redf[0];
  __syncthreads();

  const int nb = B < 16 ? B : 16;
  for (int b = 0; b < nb; ++b) {
    float lk = 0.f, lc = 0.f;
    for (int t = tid; t < T; t += 256) {
      int r = b * T + t;
      float mk = mask[r];
      lk = fmaf(rowtab[r].y, mk, lk);
      lc += mk;
    }
    __syncthreads();
    redf[tid] = lk; __syncthreads();
    for (int s = 128; s > 0; s >>= 1) { if (tid < s) redf[tid] += redf[tid + s]; __syncthreads(); }
    if (tid == 0) s_kl[b] = redf[0];
    __syncthreads();
    redf[tid] = lc; __syncthreads();
    for (int s = 128; s > 0; s >>= 1) { if (tid < s) redf[tid] += redf[tid + s]; __syncthreads(); }
    if (tid == 0) s_cnt[b] = redf[0];
    __syncthreads();
  }

  if (tid == 0) {
    float rmean = 0.f;
    for (int b = 0; b < B; ++b) rmean += rewards[b];
    rmean /= (float)B;
    float rv = 0.f;
    for (int b = 0; b < B; ++b) { float d = rewards[b] - rmean; rv += d * d; }
    float rstd = sqrtf(rv / (float)(B > 1 ? B - 1 : 1));

    float loss = 0.f, m4n = 0.f, m4d = 0.f;
    for (int b = 0; b < nb; ++b) {
      float adv  = (rewards[b] - rmean) / (rstd + 1e-8f);
      float cnt  = s_cnt[b];
      float seql = fmaxf(cnt, 1.0f);
      loss += (-adv * cnt + GRPO_BETA * s_kl[b]) / seql;
      m4n += s_kl[b];
      m4d += cnt;
    }
    loss /= (float)B;

    out[0] = loss;
    out[1] = s_mean;
    out[2] = sqrtf(s_var / (float)(M - 1));
    out[3] = s_m3;
    out[4] = m4n / m4d;
  }
}

// ---------------------------------------------------------------------------
extern "C" void kernel_launch(void* const* d_in, const int* in_sizes, int n_in,
                              void* d_out, int out_size, void* d_ws, size_t ws_size,
                              hipStream_t stream)
{
  if (n_in < 6) return;
  const float* A       = (const float*)d_in[0];
  const float* W       = (const float*)d_in[1];
  const float* mask    = (const float*)d_in[2];
  const float* rewards = (const float*)d_in[3];
  const float* rA      = (const float*)d_in[4];
  const float* rW      = (const float*)d_in[5];

  const int M = in_sizes[2];            // B*T
  const int B = in_sizes[3];
  const int T = M / B;
  const int K = in_sizes[0] / M;        // H
  const int V = in_sizes[1] / K;

  // pick NL (vocab sub-tiles per block) so partials fit in ws
  int NL = 1;
  auto need = [&](int nl) -> size_t {
    int nc = (V + BN * nl - 1) / (BN * nl);
    return (size_t)M * nc * 16 + (size_t)M * nc * 8 + (size_t)M * 16;
  };
  while (need(NL) > ws_size && NL < 1024) NL <<= 1;
  const int NC = (V + BN * NL - 1) / (BN * NL);
  const int gx = (M + BM - 1) / BM;

  float* partP  = (float*)d_ws;                    // M*NC float4
  float* partR  = partP + (size_t)M * NC * 4;      // M*NC float2
  float* rowtab = partR + (size_t)M * NC * 2;      // M float4

  dim3 g1(gx * NC), b1(512);
  mfma_gemm_reduce<true ><<<g1, b1, 0, stream>>>(A,  W,  partP, M, K, V, NC, NL, gx);
  mfma_gemm_reduce<false><<<g1, b1, 0, stream>>>(rA, rW, partR, M, K, V, NC, NL, gx);
  combine_kernel<<<dim3(M), dim3(256), 0, stream>>>(
      (const float4*)partP, (const float2*)partR, rA, rW, (float4*)rowtab, M, K, V, NC);
  final_kernel<<<dim3(1), dim3(256), 0, stream>>>(
      (const float4*)rowtab, mask, rewards, (float*)d_out, M, B, T);
}

// Round 6
// 911.552 us; speedup vs baseline: 1.7140x; 1.7140x over previous
//
#include <hip/hip_runtime.h>
#include <math.h>

#define GRPO_BETA 0.1f

constexpr int BM = 128;    // rows per block tile
constexpr int BN = 256;    // vocab cols per block tile (chunk width)
constexpr int BK = 32;     // k-slab; LDS rows hold 2 slabs (128B, double-buffered)

typedef __attribute__((ext_vector_type(4))) float   f32x4;
typedef __attribute__((ext_vector_type(8))) __bf16  bf16x8;

// NaN-safe exp for lse merges: args expected <= 0; fminf(NaN,0)=0.
__device__ __forceinline__ float sexp_fast(float a) { return __expf(fminf(a, 0.f)); }
__device__ __forceinline__ float sexp(float a)      { return expf(fminf(a, 0.f)); }

__device__ __forceinline__ bf16x8 cvt8(float4 a, float4 b) {
  bf16x8 r;
  r[0] = (__bf16)a.x; r[1] = (__bf16)a.y; r[2] = (__bf16)a.z; r[3] = (__bf16)a.w;
  r[4] = (__bf16)b.x; r[5] = (__bf16)b.y; r[6] = (__bf16)b.z; r[7] = (__bf16)b.w;
  return r;
}

// barrier WITHOUT vmcnt drain: LDS writes made visible (lgkmcnt), global
// prefetch loads stay in flight across the barrier (T4-minimum).
__device__ __forceinline__ void bar_lgkm() {
  asm volatile("s_waitcnt lgkmcnt(0)\n\ts_barrier" ::: "memory");
}

// ---------------------------------------------------------------------------
// Kernel 1: bf16-MFMA GEMM (logits = A[M,K] x W[V,K]^T), f32 inputs converted
// in-kernel, fused per-row per-256-col-chunk reductions.
// LDS layout: [row][128B]; byte x of row r lives at r*128 + (x ^ ((r&7)<<4)).
//   bytes [0,64) = even k-slab, [64,128) = odd (swizzle mixes bit 6; read and
//   write sides apply the identical involution, so it cancels).
// Staging is 16B-granule (ds_write_b128): one lane converts 8 floats ->
// bf16x8. One write instr spreads 1KB over all 32 banks (8 dwords each) ->
// conflict-free (8B-granule writes were structurally 4-way conflicted).
// Pipeline per K-step s (ONE lgkm-barrier per step):
//   MFMA(half s&1) | stage regs(slab s+1) -> other half | issue loads slab
//   s+2 | bar.   Loads stay in flight across the barrier + next MFMA phase.
// grid = (gx*NC) XCD-remapped, block = 512 (8 waves: 2M x 4N, wave tile 64x64)
// __launch_bounds__(512,4): 16 waves/CU = 2 blocks/CU; unified VGPR+AGPR
// budget 128/thread (acc=64 AGPR + ~64 arch). Small spill < occupancy loss.
// ---------------------------------------------------------------------------
template <bool POLICY>
__global__ __launch_bounds__(512, 4)
void mfma_gemm_reduce(const float* __restrict__ A,
                      const float* __restrict__ W,
                      float* __restrict__ part,
                      int M, int K, int V, int NC, int NL, int gx)
{
  __shared__ __align__(16) unsigned short lds_a[BM * 64];   // 16 KB (2 slabs)
  __shared__ __align__(16) unsigned short lds_w[BN * 64];   // 32 KB (2 slabs)
  __shared__ __align__(16) float4 lds_red[BM * 4];          // 8 KB

  const int tid  = threadIdx.x;
  const int lane = tid & 63;
  const int wave = tid >> 6;      // 0..7
  const int wm   = wave >> 2;     // 0..1  (M half)
  const int wn   = wave & 3;      // 0..3  (N quarter)
  const int l15  = lane & 15;
  const int q    = lane >> 4;     // 0..3

  // ---- XCD-aware block remap (bijective when nb % 8 == 0) ----
  const int nb  = gridDim.x;
  int wl = blockIdx.x;
  if ((nb & 7) == 0) wl = (wl & 7) * (nb >> 3) + (wl >> 3);
  const int bx    = wl % gx;
  const int chunk = wl / gx;
  const int row0  = bx * BM;

  // ---- staging map: lane covers 8 floats (k = t3*8..t3*8+7) of one row ----
  const int t3 = tid & 3;
  const int r4 = tid >> 2;        // 0..127
  // LDS write byte offset within a row (slab parity bit 6 XORed in later)
  const int stw = ((t3 * 16) ^ ((r4 & 7) << 4));
  const int sta = r4 * 128 + stw;           // A: row r4

  const int arow = min(row0 + r4, M - 1);
  const int aro  = arow * K + t3 * 8;       // A global float offset

  // ---- fragment read byte offsets (slab parity = bit 6; frag f adds 2048) ----
  const int swzr  = ((q * 16) ^ ((l15 & 7) << 4));
  const int aoff0 = (wm * 64 + l15) * 128 + swzr;
  const int woff0 = (wn * 64 + l15) * 128 + swzr;

  // running per-row records (threads 0..127 own local row = tid)
  float rm = -INFINITY, rse = 0.f, rsum = 0.f;
  int   ridx = 0x7fffffff;

  const int NS = K / BK;

  for (int sub = 0; sub < NL; ++sub) {
    const int v0 = (chunk * NL + sub) * BN;
    if (v0 >= V) break;

    int wro[2];
#pragma unroll
    for (int i = 0; i < 2; ++i)
      wro[i] = min(v0 + r4 + 128 * i, V - 1) * K + t3 * 8;

    f32x4 acc[4][4];
#pragma unroll
    for (int i = 0; i < 4; ++i)
#pragma unroll
      for (int j = 0; j < 4; ++j) acc[i][j] = (f32x4){0.f, 0.f, 0.f, 0.f};

    // ---- prologue: slab 0 -> LDS half 0; load slab 1 into regs ----
    float4 aA[2], wW[2][2];
    aA[0] = *reinterpret_cast<const float4*>(A + aro);
    aA[1] = *reinterpret_cast<const float4*>(A + aro + 4);
#pragma unroll
    for (int i = 0; i < 2; ++i) {
      wW[i][0] = *reinterpret_cast<const float4*>(W + wro[i]);
      wW[i][1] = *reinterpret_cast<const float4*>(W + wro[i] + 4);
    }
    *reinterpret_cast<bf16x8*>(reinterpret_cast<char*>(lds_a) + sta) = cvt8(aA[0], aA[1]);
#pragma unroll
    for (int i = 0; i < 2; ++i)
      *reinterpret_cast<bf16x8*>(reinterpret_cast<char*>(lds_w) + (r4 + 128 * i) * 128 + stw) =
          cvt8(wW[i][0], wW[i][1]);
    if (NS > 1) {
      aA[0] = *reinterpret_cast<const float4*>(A + aro + BK);
      aA[1] = *reinterpret_cast<const float4*>(A + aro + BK + 4);
#pragma unroll
      for (int i = 0; i < 2; ++i) {
        wW[i][0] = *reinterpret_cast<const float4*>(W + wro[i] + BK);
        wW[i][1] = *reinterpret_cast<const float4*>(W + wro[i] + BK + 4);
      }
    }
    bar_lgkm();

    // ---- main K-loop: 1 lgkm-barrier per slab ----
    for (int s = 0; s < NS; ++s) {
      const int p = (s & 1) << 6;     // LDS half of slab s

      bf16x8 afr[4];
#pragma unroll
      for (int f = 0; f < 4; ++f)
        afr[f] = *reinterpret_cast<const bf16x8*>(
            reinterpret_cast<const char*>(lds_a) + (aoff0 ^ p) + f * 2048);
      __builtin_amdgcn_s_setprio(1);
#pragma unroll
      for (int fn = 0; fn < 4; ++fn) {
        bf16x8 wfr = *reinterpret_cast<const bf16x8*>(
            reinterpret_cast<const char*>(lds_w) + (woff0 ^ p) + fn * 2048);
#pragma unroll
        for (int fm = 0; fm < 4; ++fm)
          acc[fm][fn] = __builtin_amdgcn_mfma_f32_16x16x32_bf16(
              afr[fm], wfr, acc[fm][fn], 0, 0, 0);
      }
      __builtin_amdgcn_s_setprio(0);

      if (s + 1 < NS) {
        const int p1 = ((s + 1) & 1) << 6;   // stage slab s+1 into other half
        *reinterpret_cast<bf16x8*>(reinterpret_cast<char*>(lds_a) + (sta ^ p1)) =
            cvt8(aA[0], aA[1]);
#pragma unroll
        for (int i = 0; i < 2; ++i)
          *reinterpret_cast<bf16x8*>(
              reinterpret_cast<char*>(lds_w) + (((r4 + 128 * i) * 128 + stw) ^ p1)) =
              cvt8(wW[i][0], wW[i][1]);
        if (s + 2 < NS) {                    // issue slab s+2 loads (in flight across barrier)
          const int kf = (s + 2) * BK;
          aA[0] = *reinterpret_cast<const float4*>(A + aro + kf);
          aA[1] = *reinterpret_cast<const float4*>(A + aro + kf + 4);
#pragma unroll
          for (int i = 0; i < 2; ++i) {
            wW[i][0] = *reinterpret_cast<const float4*>(W + wro[i] + kf);
            wW[i][1] = *reinterpret_cast<const float4*>(W + wro[i] + kf + 4);
          }
        }
      }
      bar_lgkm();
    }

    // ---- fused epilogue: per-row reduction over this 256-col sub-tile ----
    // C/D layout: col = lane&15, row = (lane>>4)*4 + reg  [verified m89/m91]
    // Max-first: find row max (4 shfl), THEN exp against final max; argmax by
    // exact equality + integer min.
#pragma unroll
    for (int fm = 0; fm < 4; ++fm) {
#pragma unroll
      for (int reg = 0; reg < 4; ++reg) {
        float lm = -INFINITY;
#pragma unroll
        for (int fn = 0; fn < 4; ++fn) {
          const int v = v0 + wn * 64 + fn * 16 + l15;
          if (v < V) lm = fmaxf(lm, acc[fm][fn][reg]);
        }
#pragma unroll
        for (int d = 1; d < 16; d <<= 1) lm = fmaxf(lm, __shfl_xor(lm, d));
        // lm == exact row max (within this wave's 64-col tile)
        float se = 0.f, sm = 0.f; int li = 0x7fffffff;
#pragma unroll
        for (int fn = 0; fn < 4; ++fn) {
          const int v = v0 + wn * 64 + fn * 16 + l15;
          if (v < V) {
            const float x = acc[fm][fn][reg];
            se += __expf(x - lm);
            sm += x;
            if (x == lm) li = min(li, v);
          }
        }
#pragma unroll
        for (int d = 1; d < 16; d <<= 1) {
          se += __shfl_xor(se, d);
          sm += __shfl_xor(sm, d);
          li  = min(li, __shfl_xor(li, d));
        }
        if (l15 == 0) {
          const int row = wm * 64 + fm * 16 + q * 4 + reg;
          lds_red[row * 4 + wn] = make_float4(lm, se, sm, __int_as_float(li));
        }
      }
    }
    __syncthreads();

    if (tid < BM) {
      float4 p = lds_red[tid * 4];
      float m = p.x, se = p.y, sm = p.z; int idx = __float_as_int(p.w);
#pragma unroll
      for (int j = 1; j < 4; ++j) {
        const float4 t = lds_red[tid * 4 + j];
        const int ti = __float_as_int(t.w);
        const float nm = fmaxf(m, t.x);
        se = se * sexp_fast(m - nm) + t.y * sexp_fast(t.x - nm);
        sm += t.z;
        if (t.x > m || (t.x == m && ti < idx)) idx = ti;
        m = nm;
      }
      const float nm = fmaxf(rm, m);
      rse = rse * sexp_fast(rm - nm) + se * sexp_fast(m - nm);
      rsum += sm;
      if (m > rm || (m == rm && idx < ridx)) ridx = idx;
      rm = nm;
    }
    __syncthreads();  // lds_red / lds tiles free for next sub
  }

  if (tid < BM) {
    const int row = row0 + tid;
    if (row < M) {
      if (POLICY) {
        reinterpret_cast<float4*>(part)[(size_t)row * NC + chunk] =
            make_float4(rm, rse, rsum, __int_as_float(ridx));
      } else {
        reinterpret_cast<float2*>(part)[(size_t)row * NC + chunk] =
            make_float2(rm, rse);
      }
    }
  }
}

// ---------------------------------------------------------------------------
// Kernel 2: per-row combine of chunk partials + gathered ref dot (f32 exact).
// Writes rowtab[row] = {tok_lp, kl, mean_v(log_probs_row), 0}
// grid = (M), block = 256
// ---------------------------------------------------------------------------
__global__ __launch_bounds__(256)
void combine_kernel(const float4* __restrict__ partP,
                    const float2* __restrict__ partR,
                    const float* __restrict__ refA,
                    const float* __restrict__ refW,
                    float4* __restrict__ rowtab,
                    int M, int K, int V, int NC)
{
  const int row = blockIdx.x;
  const int tid = threadIdx.x;

  __shared__ float redf[256];
  __shared__ int   redi[256];
  __shared__ float s_M, s_SE, s_SUM, s_Mr, s_SEr, s_dot;
  __shared__ int   s_idx;

  float m = -INFINITY, se = 0.f, sm = 0.f; int idx = 0x7fffffff;
  for (int i = tid; i < NC; i += 256) {
    float4 p = partP[(size_t)row * NC + i];
    int pi = __float_as_int(p.w);
    float nm = fmaxf(m, p.x);
    se = se * sexp(m - nm) + p.y * sexp(p.x - nm);
    if (p.x > m || (p.x == m && pi < idx)) idx = pi;
    m = nm;
    sm += p.z;
  }
  redf[tid] = m; redi[tid] = idx;
  __syncthreads();
  for (int s = 128; s > 0; s >>= 1) {
    if (tid < s) {
      float om = redf[tid + s]; int oi = redi[tid + s];
      if (om > redf[tid] || (om == redf[tid] && oi < redi[tid])) { redf[tid] = om; redi[tid] = oi; }
    }
    __syncthreads();
  }
  if (tid == 0) { s_M = redf[0]; s_idx = redi[0]; }
  __syncthreads();
  const float Mp = s_M; const int chosen = s_idx;

  float contrib = se * sexp(m - Mp);
  __syncthreads();
  redf[tid] = contrib; __syncthreads();
  for (int s = 128; s > 0; s >>= 1) { if (tid < s) redf[tid] += redf[tid + s]; __syncthreads(); }
  if (tid == 0) s_SE = redf[0];
  __syncthreads();
  redf[tid] = sm; __syncthreads();
  for (int s = 128; s > 0; s >>= 1) { if (tid < s) redf[tid] += redf[tid + s]; __syncthreads(); }
  if (tid == 0) s_SUM = redf[0];
  __syncthreads();

  float mr = -INFINITY, ser = 0.f;
  for (int i = tid; i < NC; i += 256) {
    float2 p = partR[(size_t)row * NC + i];
    float nm = fmaxf(mr, p.x);
    ser = ser * sexp(mr - nm) + p.y * sexp(p.x - nm);
    mr = nm;
  }
  redf[tid] = mr; __syncthreads();
  for (int s = 128; s > 0; s >>= 1) { if (tid < s) redf[tid] = fmaxf(redf[tid], redf[tid + s]); __syncthreads(); }
  if (tid == 0) s_Mr = redf[0];
  __syncthreads();
  const float Mr = s_Mr;
  float contribr = ser * sexp(mr - Mr);
  __syncthreads();
  redf[tid] = contribr; __syncthreads();
  for (int s = 128; s > 0; s >>= 1) { if (tid < s) redf[tid] += redf[tid + s]; __syncthreads(); }
  if (tid == 0) s_SEr = redf[0];
  __syncthreads();

  float dp = 0.f;
  const float* ar = refA + (size_t)row * K;
  const float* wr = refW + (size_t)chosen * K;
  for (int j = tid * 4; j < K; j += 256 * 4) {
    float4 x = *reinterpret_cast<const float4*>(ar + j);
    float4 y = *reinterpret_cast<const float4*>(wr + j);
    dp = fmaf(x.x, y.x, dp);
    dp = fmaf(x.y, y.y, dp);
    dp = fmaf(x.z, y.z, dp);
    dp = fmaf(x.w, y.w, dp);
  }
  __syncthreads();
  redf[tid] = dp; __syncthreads();
  for (int s = 128; s > 0; s >>= 1) { if (tid < s) redf[tid] += redf[tid + s]; __syncthreads(); }
  if (tid == 0) s_dot = redf[0];
  __syncthreads();

  if (tid == 0) {
    float lse     = Mp + logf(s_SE);
    float tok     = Mp - lse;
    float ref_lse = Mr + logf(s_SEr);
    float ref_tok = s_dot - ref_lse;
    float d  = ref_tok - tok;
    float kl = expm1f(d) - d;
    float rm3 = s_SUM / (float)V - lse;
    rowtab[row] = make_float4(tok, kl, rm3, 0.f);
  }
}

// ---------------------------------------------------------------------------
// Kernel 3: final reduction over rows -> 5 scalar outputs. grid=(1), block=256
// ---------------------------------------------------------------------------
__global__ __launch_bounds__(256)
void final_kernel(const float4* __restrict__ rowtab,
                  const float* __restrict__ mask,
                  const float* __restrict__ rewards,
                  float* __restrict__ out,
                  int M, int B, int T)
{
  const int tid = threadIdx.x;
  __shared__ float redf[256];
  __shared__ float s_mean, s_m3, s_var;
  __shared__ float s_kl[16], s_cnt[16];

  float st = 0.f, sm3 = 0.f;
  for (int r = tid; r < M; r += 256) {
    float4 v = rowtab[r];
    st += v.x; sm3 += v.z;
  }
  redf[tid] = st; __syncthreads();
  for (int s = 128; s > 0; s >>= 1) { if (tid < s) redf[tid] += redf[tid + s]; __syncthreads(); }
  if (tid == 0) s_mean = redf[0] / (float)M;
  __syncthreads();
  redf[tid] = sm3; __syncthreads();
  for (int s = 128; s > 0; s >>= 1) { if (tid < s) redf[tid] += redf[tid + s]; __syncthreads(); }
  if (tid == 0) s_m3 = redf[0] / (float)M;
  __syncthreads();

  const float mean = s_mean;
  float sv = 0.f;
  for (int r = tid; r < M; r += 256) { float d = rowtab[r].x - mean; sv = fmaf(d, d, sv); }
  __syncthreads();
  redf[tid] = sv; __syncthreads();
  for (int s = 128; s > 0; s >>= 1) { if (tid < s) redf[tid] += redf[tid + s]; __syncthreads(); }
  if (tid == 0) s_var = redf[0];
  __syncthreads();

  const int nb = B < 16 ? B : 16;
  for (int b = 0; b < nb; ++b) {
    float lk = 0.f, lc = 0.f;
    for (int t = tid; t < T; t += 256) {
      int r = b * T + t;
      float mk = mask[r];
      lk = fmaf(rowtab[r].y, mk, lk);
      lc += mk;
    }
    __syncthreads();
    redf[tid] = lk; __syncthreads();
    for (int s = 128; s > 0; s >>= 1) { if (tid < s) redf[tid] += redf[tid + s]; __syncthreads(); }
    if (tid == 0) s_kl[b] = redf[0];
    __syncthreads();
    redf[tid] = lc; __syncthreads();
    for (int s = 128; s > 0; s >>= 1) { if (tid < s) redf[tid] += redf[tid + s]; __syncthreads(); }
    if (tid == 0) s_cnt[b] = redf[0];
    __syncthreads();
  }

  if (tid == 0) {
    float rmean = 0.f;
    for (int b = 0; b < B; ++b) rmean += rewards[b];
    rmean /= (float)B;
    float rv = 0.f;
    for (int b = 0; b < B; ++b) { float d = rewards[b] - rmean; rv += d * d; }
    float rstd = sqrtf(rv / (float)(B > 1 ? B - 1 : 1));

    float loss = 0.f, m4n = 0.f, m4d = 0.f;
    for (int b = 0; b < nb; ++b) {
      float adv  = (rewards[b] - rmean) / (rstd + 1e-8f);
      float cnt  = s_cnt[b];
      float seql = fmaxf(cnt, 1.0f);
      loss += (-adv * cnt + GRPO_BETA * s_kl[b]) / seql;
      m4n += s_kl[b];
      m4d += cnt;
    }
    loss /= (float)B;

    out[0] = loss;
    out[1] = s_mean;
    out[2] = sqrtf(s_var / (float)(M - 1));
    out[3] = s_m3;
    out[4] = m4n / m4d;
  }
}

// ---------------------------------------------------------------------------
extern "C" void kernel_launch(void* const* d_in, const int* in_sizes, int n_in,
                              void* d_out, int out_size, void* d_ws, size_t ws_size,
                              hipStream_t stream)
{
  if (n_in < 6) return;
  const float* A       = (const float*)d_in[0];
  const float* W       = (const float*)d_in[1];
  const float* mask    = (const float*)d_in[2];
  const float* rewards = (const float*)d_in[3];
  const float* rA      = (const float*)d_in[4];
  const float* rW      = (const float*)d_in[5];

  const int M = in_sizes[2];            // B*T
  const int B = in_sizes[3];
  const int T = M / B;
  const int K = in_sizes[0] / M;        // H
  const int V = in_sizes[1] / K;

  // pick NL (vocab sub-tiles per block) so partials fit in ws
  int NL = 1;
  auto need = [&](int nl) -> size_t {
    int nc = (V + BN * nl - 1) / (BN * nl);
    return (size_t)M * nc * 16 + (size_t)M * nc * 8 + (size_t)M * 16;
  };
  while (need(NL) > ws_size && NL < 1024) NL <<= 1;
  const int NC = (V + BN * NL - 1) / (BN * NL);
  const int gx = (M + BM - 1) / BM;

  float* partP  = (float*)d_ws;                    // M*NC float4
  float* partR  = partP + (size_t)M * NC * 4;      // M*NC float2
  float* rowtab = partR + (size_t)M * NC * 2;      // M float4

  dim3 g1(gx * NC), b1(512);
  mfma_gemm_reduce<true ><<<g1, b1, 0, stream>>>(A,  W,  partP, M, K, V, NC, NL, gx);
  mfma_gemm_reduce<false><<<g1, b1, 0, stream>>>(rA, rW, partR, M, K, V, NC, NL, gx);
  combine_kernel<<<dim3(M), dim3(256), 0, stream>>>(
      (const float4*)partP, (const float2*)partR, rA, rW, (float4*)rowtab, M, K, V, NC);
  final_kernel<<<dim3(1), dim3(256), 0, stream>>>(
      (const float4*)rowtab, mask, rewards, (float*)d_out, M, B, T);
}

// Round 7
// 876.423 us; speedup vs baseline: 1.7827x; 1.0401x over previous
//
#include <hip/hip_runtime.h>
#include <math.h>

#define GRPO_BETA 0.1f

constexpr int BM = 128;    // rows per block tile
constexpr int BN = 256;    // vocab cols per block tile (chunk width)
constexpr int BK = 32;     // k-slab; LDS rows hold 2 slabs (128B, double-buffered)

typedef __attribute__((ext_vector_type(4))) float   f32x4;
typedef __attribute__((ext_vector_type(8))) __bf16  bf16x8;

// NaN-safe exp for lse merges: args expected <= 0; fminf(NaN,0)=0.
__device__ __forceinline__ float sexp_fast(float a) { return __expf(fminf(a, 0.f)); }
__device__ __forceinline__ float sexp(float a)      { return expf(fminf(a, 0.f)); }

__device__ __forceinline__ bf16x8 cvt8(float4 a, float4 b) {
  bf16x8 r;
  r[0] = (__bf16)a.x; r[1] = (__bf16)a.y; r[2] = (__bf16)a.z; r[3] = (__bf16)a.w;
  r[4] = (__bf16)b.x; r[5] = (__bf16)b.y; r[6] = (__bf16)b.z; r[7] = (__bf16)b.w;
  return r;
}

// barrier WITHOUT vmcnt drain: LDS writes made visible (lgkmcnt), global
// prefetch loads stay in flight across the barrier (T4-minimum).
__device__ __forceinline__ void bar_lgkm() {
  asm volatile("s_waitcnt lgkmcnt(0)\n\ts_barrier" ::: "memory");
}

// ---------------------------------------------------------------------------
// Kernel 0: f32 -> bf16 conversion (grid-stride, 16B loads x2 -> 16B store).
// Deduplicates the in-GEMM conversion (W was converted 16x, A 250x).
// ---------------------------------------------------------------------------
__global__ __launch_bounds__(256)
void cvt_bf16_kernel(const float* __restrict__ src, __bf16* __restrict__ dst,
                     long long n8)
{
  long long i = (long long)blockIdx.x * blockDim.x + threadIdx.x;
  const long long stride = (long long)gridDim.x * blockDim.x;
  for (; i < n8; i += stride) {
    const float4 a = *reinterpret_cast<const float4*>(src + i * 8);
    const float4 b = *reinterpret_cast<const float4*>(src + i * 8 + 4);
    *reinterpret_cast<bf16x8*>(dst + i * 8) = cvt8(a, b);
  }
}

// ---------------------------------------------------------------------------
// Kernel 1: bf16-MFMA GEMM (logits = A[M,K] x W[V,K]^T) fused with per-row
// per-256-col-chunk reductions.
// CVT=true : inputs are f32, converted in-loop (fallback when ws too small).
// CVT=false: inputs are pre-converted bf16 (no cvt in hot loop, half fetch).
// LDS layout: [row][128B]; byte x of row r lives at r*128 + (x ^ ((r&7)<<4)).
//   bytes [0,64) = even k-slab, [64,128) = odd (read/write apply the same
//   involution; residual 2-way bank aliasing on reads is free, m136).
// Pipeline per K-step s (ONE lgkm-barrier per step):
//   MFMA(half s&1) | stage regs(slab s+1) -> other half | issue loads slab
//   s+2 | bar.   Loads stay in flight across the barrier + next MFMA phase.
// grid = (gx*NC) XCD-remapped, block = 512 (8 waves: 2M x 4N, wave tile 64x64)
// __launch_bounds__(512,4): 16 waves/CU = 2 blocks/CU (LDS also caps at 2).
// ---------------------------------------------------------------------------
template <bool POLICY, bool CVT>
__global__ __launch_bounds__(512, 4)
void mfma_gemm_reduce(const float* __restrict__ Af,
                      const __bf16* __restrict__ Ah,
                      const float* __restrict__ Wf,
                      const __bf16* __restrict__ Wh,
                      float* __restrict__ part,
                      int M, int K, int V, int NC, int NL, int gx)
{
  __shared__ __align__(16) unsigned short lds_a[BM * 64];   // 16 KB (2 slabs)
  __shared__ __align__(16) unsigned short lds_w[BN * 64];   // 32 KB (2 slabs)
  __shared__ __align__(16) float4 lds_red[BM * 4];          // 8 KB

  const int tid  = threadIdx.x;
  const int lane = tid & 63;
  const int wave = tid >> 6;      // 0..7
  const int wm   = wave >> 2;     // 0..1  (M half)
  const int wn   = wave & 3;      // 0..3  (N quarter)
  const int l15  = lane & 15;
  const int q    = lane >> 4;     // 0..3

  // ---- XCD-aware block remap (bijective when nb % 8 == 0) ----
  const int nb  = gridDim.x;
  int wl = blockIdx.x;
  if ((nb & 7) == 0) wl = (wl & 7) * (nb >> 3) + (wl >> 3);
  const int bx    = wl % gx;
  const int chunk = wl / gx;
  const int row0  = bx * BM;

  // ---- staging map: lane covers 8 k-elems (16B bf16 / 32B f32) of one row ----
  const int t3 = tid & 3;
  const int r4 = tid >> 2;        // 0..127
  const int stw = ((t3 * 16) ^ ((r4 & 7) << 4));  // byte off in row (pre-parity)
  const int sta = r4 * 128 + stw;                  // A: row r4

  const int arow = min(row0 + r4, M - 1);
  const int aro  = arow * K + t3 * 8;              // element offset

  // ---- fragment read byte offsets (slab parity = bit 6; frag f adds 2048) ----
  const int swzr  = ((q * 16) ^ ((l15 & 7) << 4));
  const int aoff0 = (wm * 64 + l15) * 128 + swzr;
  const int woff0 = (wn * 64 + l15) * 128 + swzr;

  // running per-row records (threads 0..127 own local row = tid)
  float rm = -INFINITY, rse = 0.f, rsum = 0.f;
  int   ridx = 0x7fffffff;

  const int NS = K / BK;

  for (int sub = 0; sub < NL; ++sub) {
    const int v0 = (chunk * NL + sub) * BN;
    if (v0 >= V) break;

    int wro[2];
#pragma unroll
    for (int i = 0; i < 2; ++i)
      wro[i] = min(v0 + r4 + 128 * i, V - 1) * K + t3 * 8;

    f32x4 acc[4][4];
#pragma unroll
    for (int i = 0; i < 4; ++i)
#pragma unroll
      for (int j = 0; j < 4; ++j) acc[i][j] = (f32x4){0.f, 0.f, 0.f, 0.f};

    // prefetch registers
    float4 aF[2], wF[2][2];     // CVT=true
    bf16x8 aH, wH[2];           // CVT=false

    // ---- prologue: slab 0 -> LDS half 0; load slab 1 into regs ----
    if constexpr (CVT) {
      aF[0] = *reinterpret_cast<const float4*>(Af + aro);
      aF[1] = *reinterpret_cast<const float4*>(Af + aro + 4);
#pragma unroll
      for (int i = 0; i < 2; ++i) {
        wF[i][0] = *reinterpret_cast<const float4*>(Wf + wro[i]);
        wF[i][1] = *reinterpret_cast<const float4*>(Wf + wro[i] + 4);
      }
      *reinterpret_cast<bf16x8*>(reinterpret_cast<char*>(lds_a) + sta) = cvt8(aF[0], aF[1]);
#pragma unroll
      for (int i = 0; i < 2; ++i)
        *reinterpret_cast<bf16x8*>(reinterpret_cast<char*>(lds_w) + (r4 + 128 * i) * 128 + stw) =
            cvt8(wF[i][0], wF[i][1]);
      if (NS > 1) {
        aF[0] = *reinterpret_cast<const float4*>(Af + aro + BK);
        aF[1] = *reinterpret_cast<const float4*>(Af + aro + BK + 4);
#pragma unroll
        for (int i = 0; i < 2; ++i) {
          wF[i][0] = *reinterpret_cast<const float4*>(Wf + wro[i] + BK);
          wF[i][1] = *reinterpret_cast<const float4*>(Wf + wro[i] + BK + 4);
        }
      }
    } else {
      aH = *reinterpret_cast<const bf16x8*>(Ah + aro);
#pragma unroll
      for (int i = 0; i < 2; ++i)
        wH[i] = *reinterpret_cast<const bf16x8*>(Wh + wro[i]);
      *reinterpret_cast<bf16x8*>(reinterpret_cast<char*>(lds_a) + sta) = aH;
#pragma unroll
      for (int i = 0; i < 2; ++i)
        *reinterpret_cast<bf16x8*>(reinterpret_cast<char*>(lds_w) + (r4 + 128 * i) * 128 + stw) = wH[i];
      if (NS > 1) {
        aH = *reinterpret_cast<const bf16x8*>(Ah + aro + BK);
#pragma unroll
        for (int i = 0; i < 2; ++i)
          wH[i] = *reinterpret_cast<const bf16x8*>(Wh + wro[i] + BK);
      }
    }
    bar_lgkm();

    // ---- main K-loop: 1 lgkm-barrier per slab ----
    for (int s = 0; s < NS; ++s) {
      const int p = (s & 1) << 6;     // LDS half of slab s

      bf16x8 afr[4];
#pragma unroll
      for (int f = 0; f < 4; ++f)
        afr[f] = *reinterpret_cast<const bf16x8*>(
            reinterpret_cast<const char*>(lds_a) + (aoff0 ^ p) + f * 2048);
      __builtin_amdgcn_s_setprio(1);
#pragma unroll
      for (int fn = 0; fn < 4; ++fn) {
        bf16x8 wfr = *reinterpret_cast<const bf16x8*>(
            reinterpret_cast<const char*>(lds_w) + (woff0 ^ p) + fn * 2048);
#pragma unroll
        for (int fm = 0; fm < 4; ++fm)
          acc[fm][fn] = __builtin_amdgcn_mfma_f32_16x16x32_bf16(
              afr[fm], wfr, acc[fm][fn], 0, 0, 0);
      }
      __builtin_amdgcn_s_setprio(0);

      if (s + 1 < NS) {
        const int p1 = ((s + 1) & 1) << 6;   // stage slab s+1 into other half
        if constexpr (CVT) {
          *reinterpret_cast<bf16x8*>(reinterpret_cast<char*>(lds_a) + (sta ^ p1)) =
              cvt8(aF[0], aF[1]);
#pragma unroll
          for (int i = 0; i < 2; ++i)
            *reinterpret_cast<bf16x8*>(
                reinterpret_cast<char*>(lds_w) + (((r4 + 128 * i) * 128 + stw) ^ p1)) =
                cvt8(wF[i][0], wF[i][1]);
          if (s + 2 < NS) {                  // issue slab s+2 loads
            const int kf = (s + 2) * BK;
            aF[0] = *reinterpret_cast<const float4*>(Af + aro + kf);
            aF[1] = *reinterpret_cast<const float4*>(Af + aro + kf + 4);
#pragma unroll
            for (int i = 0; i < 2; ++i) {
              wF[i][0] = *reinterpret_cast<const float4*>(Wf + wro[i] + kf);
              wF[i][1] = *reinterpret_cast<const float4*>(Wf + wro[i] + kf + 4);
            }
          }
        } else {
          *reinterpret_cast<bf16x8*>(reinterpret_cast<char*>(lds_a) + (sta ^ p1)) = aH;
#pragma unroll
          for (int i = 0; i < 2; ++i)
            *reinterpret_cast<bf16x8*>(
                reinterpret_cast<char*>(lds_w) + (((r4 + 128 * i) * 128 + stw) ^ p1)) = wH[i];
          if (s + 2 < NS) {                  // issue slab s+2 loads
            const int kf = (s + 2) * BK;
            aH = *reinterpret_cast<const bf16x8*>(Ah + aro + kf);
#pragma unroll
            for (int i = 0; i < 2; ++i)
              wH[i] = *reinterpret_cast<const bf16x8*>(Wh + wro[i] + kf);
          }
        }
      }
      bar_lgkm();
    }

    // ---- fused epilogue: per-row reduction over this 256-col sub-tile ----
    // C/D layout: col = lane&15, row = (lane>>4)*4 + reg  [verified m89/m91]
#pragma unroll
    for (int fm = 0; fm < 4; ++fm) {
#pragma unroll
      for (int reg = 0; reg < 4; ++reg) {
        float lm = -INFINITY;
#pragma unroll
        for (int fn = 0; fn < 4; ++fn) {
          const int v = v0 + wn * 64 + fn * 16 + l15;
          if (v < V) lm = fmaxf(lm, acc[fm][fn][reg]);
        }
#pragma unroll
        for (int d = 1; d < 16; d <<= 1) lm = fmaxf(lm, __shfl_xor(lm, d));
        // lm == exact row max (within this wave's 64-col tile)
        float se = 0.f, sm = 0.f; int li = 0x7fffffff;
#pragma unroll
        for (int fn = 0; fn < 4; ++fn) {
          const int v = v0 + wn * 64 + fn * 16 + l15;
          if (v < V) {
            const float x = acc[fm][fn][reg];
            se += __expf(x - lm);
            sm += x;
            if (x == lm) li = min(li, v);
          }
        }
#pragma unroll
        for (int d = 1; d < 16; d <<= 1) {
          se += __shfl_xor(se, d);
          sm += __shfl_xor(sm, d);
          li  = min(li, __shfl_xor(li, d));
        }
        if (l15 == 0) {
          const int row = wm * 64 + fm * 16 + q * 4 + reg;
          lds_red[row * 4 + wn] = make_float4(lm, se, sm, __int_as_float(li));
        }
      }
    }
    __syncthreads();

    if (tid < BM) {
      float4 p = lds_red[tid * 4];
      float m = p.x, se = p.y, sm = p.z; int idx = __float_as_int(p.w);
#pragma unroll
      for (int j = 1; j < 4; ++j) {
        const float4 t = lds_red[tid * 4 + j];
        const int ti = __float_as_int(t.w);
        const float nm = fmaxf(m, t.x);
        se = se * sexp_fast(m - nm) + t.y * sexp_fast(t.x - nm);
        sm += t.z;
        if (t.x > m || (t.x == m && ti < idx)) idx = ti;
        m = nm;
      }
      const float nm = fmaxf(rm, m);
      rse = rse * sexp_fast(rm - nm) + se * sexp_fast(m - nm);
      rsum += sm;
      if (m > rm || (m == rm && idx < ridx)) ridx = idx;
      rm = nm;
    }
    __syncthreads();  // lds_red / lds tiles free for next sub
  }

  if (tid < BM) {
    const int row = row0 + tid;
    if (row < M) {
      if (POLICY) {
        reinterpret_cast<float4*>(part)[(size_t)row * NC + chunk] =
            make_float4(rm, rse, rsum, __int_as_float(ridx));
      } else {
        reinterpret_cast<float2*>(part)[(size_t)row * NC + chunk] =
            make_float2(rm, rse);
      }
    }
  }
}

// ---------------------------------------------------------------------------
// Kernel 2: per-row combine of chunk partials + gathered ref dot (f32 exact).
// Writes rowtab[row] = {tok_lp, kl, mean_v(log_probs_row), 0}
// grid = (M), block = 256
// ---------------------------------------------------------------------------
__global__ __launch_bounds__(256)
void combine_kernel(const float4* __restrict__ partP,
                    const float2* __restrict__ partR,
                    const float* __restrict__ refA,
                    const float* __restrict__ refW,
                    float4* __restrict__ rowtab,
                    int M, int K, int V, int NC)
{
  const int row = blockIdx.x;
  const int tid = threadIdx.x;

  __shared__ float redf[256];
  __shared__ int   redi[256];
  __shared__ float s_M, s_SE, s_SUM, s_Mr, s_SEr, s_dot;
  __shared__ int   s_idx;

  float m = -INFINITY, se = 0.f, sm = 0.f; int idx = 0x7fffffff;
  for (int i = tid; i < NC; i += 256) {
    float4 p = partP[(size_t)row * NC + i];
    int pi = __float_as_int(p.w);
    float nm = fmaxf(m, p.x);
    se = se * sexp(m - nm) + p.y * sexp(p.x - nm);
    if (p.x > m || (p.x == m && pi < idx)) idx = pi;
    m = nm;
    sm += p.z;
  }
  redf[tid] = m; redi[tid] = idx;
  __syncthreads();
  for (int s = 128; s > 0; s >>= 1) {
    if (tid < s) {
      float om = redf[tid + s]; int oi = redi[tid + s];
      if (om > redf[tid] || (om == redf[tid] && oi < redi[tid])) { redf[tid] = om; redi[tid] = oi; }
    }
    __syncthreads();
  }
  if (tid == 0) { s_M = redf[0]; s_idx = redi[0]; }
  __syncthreads();
  const float Mp = s_M; const int chosen = s_idx;

  float contrib = se * sexp(m - Mp);
  __syncthreads();
  redf[tid] = contrib; __syncthreads();
  for (int s = 128; s > 0; s >>= 1) { if (tid < s) redf[tid] += redf[tid + s]; __syncthreads(); }
  if (tid == 0) s_SE = redf[0];
  __syncthreads();
  redf[tid] = sm; __syncthreads();
  for (int s = 128; s > 0; s >>= 1) { if (tid < s) redf[tid] += redf[tid + s]; __syncthreads(); }
  if (tid == 0) s_SUM = redf[0];
  __syncthreads();

  float mr = -INFINITY, ser = 0.f;
  for (int i = tid; i < NC; i += 256) {
    float2 p = partR[(size_t)row * NC + i];
    float nm = fmaxf(mr, p.x);
    ser = ser * sexp(mr - nm) + p.y * sexp(p.x - nm);
    mr = nm;
  }
  redf[tid] = mr; __syncthreads();
  for (int s = 128; s > 0; s >>= 1) { if (tid < s) redf[tid] = fmaxf(redf[tid], redf[tid + s]); __syncthreads(); }
  if (tid == 0) s_Mr = redf[0];
  __syncthreads();
  const float Mr = s_Mr;
  float contribr = ser * sexp(mr - Mr);
  __syncthreads();
  redf[tid] = contribr; __syncthreads();
  for (int s = 128; s > 0; s >>= 1) { if (tid < s) redf[tid] += redf[tid + s]; __syncthreads(); }
  if (tid == 0) s_SEr = redf[0];
  __syncthreads();

  float dp = 0.f;
  const float* ar = refA + (size_t)row * K;
  const float* wr = refW + (size_t)chosen * K;
  for (int j = tid * 4; j < K; j += 256 * 4) {
    float4 x = *reinterpret_cast<const float4*>(ar + j);
    float4 y = *reinterpret_cast<const float4*>(wr + j);
    dp = fmaf(x.x, y.x, dp);
    dp = fmaf(x.y, y.y, dp);
    dp = fmaf(x.z, y.z, dp);
    dp = fmaf(x.w, y.w, dp);
  }
  __syncthreads();
  redf[tid] = dp; __syncthreads();
  for (int s = 128; s > 0; s >>= 1) { if (tid < s) redf[tid] += redf[tid + s]; __syncthreads(); }
  if (tid == 0) s_dot = redf[0];
  __syncthreads();

  if (tid == 0) {
    float lse     = Mp + logf(s_SE);
    float tok     = Mp - lse;
    float ref_lse = Mr + logf(s_SEr);
    float ref_tok = s_dot - ref_lse;
    float d  = ref_tok - tok;
    float kl = expm1f(d) - d;
    float rm3 = s_SUM / (float)V - lse;
    rowtab[row] = make_float4(tok, kl, rm3, 0.f);
  }
}

// ---------------------------------------------------------------------------
// Kernel 3: final reduction over rows -> 5 scalar outputs. grid=(1), block=256
// ---------------------------------------------------------------------------
__global__ __launch_bounds__(256)
void final_kernel(const float4* __restrict__ rowtab,
                  const float* __restrict__ mask,
                  const float* __restrict__ rewards,
                  float* __restrict__ out,
                  int M, int B, int T)
{
  const int tid = threadIdx.x;
  __shared__ float redf[256];
  __shared__ float s_mean, s_m3, s_var;
  __shared__ float s_kl[16], s_cnt[16];

  float st = 0.f, sm3 = 0.f;
  for (int r = tid; r < M; r += 256) {
    float4 v = rowtab[r];
    st += v.x; sm3 += v.z;
  }
  redf[tid] = st; __syncthreads();
  for (int s = 128; s > 0; s >>= 1) { if (tid < s) redf[tid] += redf[tid + s]; __syncthreads(); }
  if (tid == 0) s_mean = redf[0] / (float)M;
  __syncthreads();
  redf[tid] = sm3; __syncthreads();
  for (int s = 128; s > 0; s >>= 1) { if (tid < s) redf[tid] += redf[tid + s]; __syncthreads(); }
  if (tid == 0) s_m3 = redf[0] / (float)M;
  __syncthreads();

  const float mean = s_mean;
  float sv = 0.f;
  for (int r = tid; r < M; r += 256) { float d = rowtab[r].x - mean; sv = fmaf(d, d, sv); }
  __syncthreads();
  redf[tid] = sv; __syncthreads();
  for (int s = 128; s > 0; s >>= 1) { if (tid < s) redf[tid] += redf[tid + s]; __syncthreads(); }
  if (tid == 0) s_var = redf[0];
  __syncthreads();

  const int nb = B < 16 ? B : 16;
  for (int b = 0; b < nb; ++b) {
    float lk = 0.f, lc = 0.f;
    for (int t = tid; t < T; t += 256) {
      int r = b * T + t;
      float mk = mask[r];
      lk = fmaf(rowtab[r].y, mk, lk);
      lc += mk;
    }
    __syncthreads();
    redf[tid] = lk; __syncthreads();
    for (int s = 128; s > 0; s >>= 1) { if (tid < s) redf[tid] += redf[tid + s]; __syncthreads(); }
    if (tid == 0) s_kl[b] = redf[0];
    __syncthreads();
    redf[tid] = lc; __syncthreads();
    for (int s = 128; s > 0; s >>= 1) { if (tid < s) redf[tid] += redf[tid + s]; __syncthreads(); }
    if (tid == 0) s_cnt[b] = redf[0];
    __syncthreads();
  }

  if (tid == 0) {
    float rmean = 0.f;
    for (int b = 0; b < B; ++b) rmean += rewards[b];
    rmean /= (float)B;
    float rv = 0.f;
    for (int b = 0; b < B; ++b) { float d = rewards[b] - rmean; rv += d * d; }
    float rstd = sqrtf(rv / (float)(B > 1 ? B - 1 : 1));

    float loss = 0.f, m4n = 0.f, m4d = 0.f;
    for (int b = 0; b < nb; ++b) {
      float adv  = (rewards[b] - rmean) / (rstd + 1e-8f);
      float cnt  = s_cnt[b];
      float seql = fmaxf(cnt, 1.0f);
      loss += (-adv * cnt + GRPO_BETA * s_kl[b]) / seql;
      m4n += s_kl[b];
      m4d += cnt;
    }
    loss /= (float)B;

    out[0] = loss;
    out[1] = s_mean;
    out[2] = sqrtf(s_var / (float)(M - 1));
    out[3] = s_m3;
    out[4] = m4n / m4d;
  }
}

// ---------------------------------------------------------------------------
extern "C" void kernel_launch(void* const* d_in, const int* in_sizes, int n_in,
                              void* d_out, int out_size, void* d_ws, size_t ws_size,
                              hipStream_t stream)
{
  if (n_in < 6) return;
  const float* A       = (const float*)d_in[0];
  const float* W       = (const float*)d_in[1];
  const float* mask    = (const float*)d_in[2];
  const float* rewards = (const float*)d_in[3];
  const float* rA      = (const float*)d_in[4];
  const float* rW      = (const float*)d_in[5];

  const int M = in_sizes[2];            // B*T
  const int B = in_sizes[3];
  const int T = M / B;
  const int K = in_sizes[0] / M;        // H
  const int V = in_sizes[1] / K;

  const int gx = (M + BM - 1) / BM;

  // ---- workspace budgeting ----
  const size_t aBytes = (size_t)M * K * sizeof(__bf16);   // bf16 mirror of A
  const size_t wBytes = (size_t)V * K * sizeof(__bf16);   // bf16 mirror of W
  auto partBytes = [&](int nl) -> size_t {
    int nc = (V + BN * nl - 1) / (BN * nl);
    return (size_t)M * nc * 16 + (size_t)M * nc * 8 + (size_t)M * 16;
  };
  const bool canPrep =
      (K % 8 == 0) && (partBytes(1) + 2 * aBytes + 2 * wBytes <= ws_size);

  int NL = 1;
  if (!canPrep) {
    while (partBytes(NL) > ws_size && NL < 1024) NL <<= 1;
  }
  const int NC = (V + BN * NL - 1) / (BN * NL);

  float* partP  = (float*)d_ws;                    // M*NC float4
  float* partR  = partP + (size_t)M * NC * 4;      // M*NC float2
  float* rowtab = partR + (size_t)M * NC * 2;      // M float4

  dim3 g1(gx * NC), b1(512);

  if (canPrep) {
    __bf16* Ab  = (__bf16*)(rowtab + (size_t)M * 4);
    __bf16* rAb = Ab  + (size_t)M * K;
    __bf16* Wb  = rAb + (size_t)M * K;
    __bf16* rWb = Wb  + (size_t)V * K;

    const long long nA8 = (long long)M * K / 8;
    const long long nW8 = (long long)V * K / 8;
    cvt_bf16_kernel<<<dim3(512),  dim3(256), 0, stream>>>(A,  Ab,  nA8);
    cvt_bf16_kernel<<<dim3(512),  dim3(256), 0, stream>>>(rA, rAb, nA8);
    cvt_bf16_kernel<<<dim3(2048), dim3(256), 0, stream>>>(W,  Wb,  nW8);
    cvt_bf16_kernel<<<dim3(2048), dim3(256), 0, stream>>>(rW, rWb, nW8);

    mfma_gemm_reduce<true , false><<<g1, b1, 0, stream>>>(
        nullptr, Ab,  nullptr, Wb,  partP, M, K, V, NC, NL, gx);
    mfma_gemm_reduce<false, false><<<g1, b1, 0, stream>>>(
        nullptr, rAb, nullptr, rWb, partR, M, K, V, NC, NL, gx);
  } else {
    mfma_gemm_reduce<true , true><<<g1, b1, 0, stream>>>(
        A,  nullptr, W,  nullptr, partP, M, K, V, NC, NL, gx);
    mfma_gemm_reduce<false, true><<<g1, b1, 0, stream>>>(
        rA, nullptr, rW, nullptr, partR, M, K, V, NC, NL, gx);
  }

  combine_kernel<<<dim3(M), dim3(256), 0, stream>>>(
      (const float4*)partP, (const float2*)partR, rA, rW, (float4*)rowtab, M, K, V, NC);
  final_kernel<<<dim3(1), dim3(256), 0, stream>>>(
      (const float4*)rowtab, mask, rewards, (float*)d_out, M, B, T);
}